// Round 1
// baseline (363.814 us; speedup 1.0000x reference)
//
#include <hip/hip_runtime.h>

#define LOG2E 1.4426950408889634f

constexpr int TN     = 100000;
constexpr int CHUNKS = 1000;
constexpr int CLEN   = 100;   // CHUNKS*CLEN == TN
constexpr int GROUPS = 40;
constexpr int GSIZE  = 25;    // GROUPS*GSIZE == CHUNKS

// float offsets into ws
constexpr size_t OFF_W   = 0;                              // 32x32
constexpr size_t OFF_W2  = 1024;                           // 32x32
constexpr size_t OFF_I2V = 2048;                           // 32
constexpr size_t OFF_CT  = 4096;                           // TN
constexpr size_t OFF_Q   = OFF_CT + TN;                    // CHUNKS*1024
constexpr size_t OFF_R   = OFF_Q + (size_t)CHUNKS * 1024;  // GROUPS*1024
constexpr size_t OFF_XG  = OFF_R + (size_t)GROUPS * 1024;  // GROUPS*32
constexpr size_t OFF_E0  = OFF_XG + (size_t)GROUPS * 32;   // CHUNKS*32

// ---------------------------------------------------------------------------
// Prep: cts[t] = obs2[t] - bate*obs1[t]  (blocks 0..390)
//       W, W2, inv2v                     (block 391)
// ---------------------------------------------------------------------------
__global__ __launch_bounds__(256) void k_prep(
    const float* __restrict__ obs2, const float* __restrict__ obs1,
    const float* __restrict__ mean, const float* __restrict__ var,
    const float* __restrict__ bate_p, const float* __restrict__ aij,
    float* __restrict__ ws)
{
  const int b = blockIdx.x, tid = threadIdx.x;
  const int nct = (TN + 255) / 256;
  if (b < nct) {
    int t = b * 256 + tid;
    if (t < TN) ws[OFF_CT + t] = obs2[t] - bate_p[0] * obs1[t];
  } else {
    const int j = tid & 31, ig = tid >> 5;
    float vj   = var[j];
    float i2v  = 0.5f / vj;
    float norm = rsqrtf(2.0f * 3.1415926f * vj);
    float Aj   = norm * expf(mean[j] * i2v);
    float bate = bate_p[0];
    if (tid < 32) ws[OFF_I2V + tid] = i2v;
#pragma unroll
    for (int m = 0; m < 4; ++m) {
      int i = ig * 4 + m;
      float Bij = expf(-bate * mean[i] * i2v);
      float w = aij[i * 32 + j] * Aj * Bij;
      ws[OFF_W  + i * 32 + j] = w;
      ws[OFF_W2 + i * 32 + j] = w * Aj * Bij;
    }
  }
}

// ---------------------------------------------------------------------------
// Phase 1: per-chunk transfer matrix  Q_c = M_{t_end-1} ... M_{t_start},
// M_t[j,k] = u_t[j] * W[k,j].   Q_new[j,i] = u_j * sum_k W[k,j] * Q[k,i].
// 256 threads: thread (j, ig) owns row j, cols [4*ig, 4*ig+4).
// ---------------------------------------------------------------------------
__global__ __launch_bounds__(256) void k_phase1(float* __restrict__ ws)
{
  const int b = blockIdx.x, tid = threadIdx.x;
  const int j = tid & 31, i0 = (tid >> 5) * 4;
  const float* Wg  = ws + OFF_W;
  const float* cts = ws + OFF_CT;
  __shared__ __align__(16) float Q[2][32][36];
  __shared__ float red[4];
  float Wc[32];
#pragma unroll
  for (int k = 0; k < 32; ++k) Wc[k] = Wg[k * 32 + j];
  const float i2v = ws[OFF_I2V + j];
#pragma unroll
  for (int m = 0; m < 4; ++m) Q[0][j][i0 + m] = (j == i0 + m) ? 1.0f : 0.0f;
  __syncthreads();
  int buf = 0;
  const int t0 = b * CLEN;
  for (int s = 0; s < CLEN; ++s) {
    float ct = cts[t0 + s];
    float u  = exp2f(-ct * i2v * LOG2E);
    float a0 = 0.f, a1 = 0.f, a2 = 0.f, a3 = 0.f;
#pragma unroll
    for (int k = 0; k < 32; ++k) {
      float4 q = *(const float4*)&Q[buf][k][i0];
      float w = Wc[k];
      a0 += w * q.x; a1 += w * q.y; a2 += w * q.z; a3 += w * q.w;
    }
    a0 *= u; a1 *= u; a2 *= u; a3 *= u;
    if ((s & 3) == 3) {  // rescale to keep fp32 range (scale-invariant overall)
      float ps = a0 + a1 + a2 + a3;
#pragma unroll
      for (int o = 1; o < 64; o <<= 1) ps += __shfl_xor(ps, o);
      if ((tid & 63) == 0) red[tid >> 6] = ps;
      __syncthreads();
      float g = __builtin_amdgcn_rcpf(red[0] + red[1] + red[2] + red[3]);
      a0 *= g; a1 *= g; a2 *= g; a3 *= g;
    }
    float4 o4 = {a0, a1, a2, a3};
    *(float4*)&Q[buf ^ 1][j][i0] = o4;
    __syncthreads();
    buf ^= 1;
  }
  float* Qo = ws + OFF_Q + (size_t)b * 1024;
#pragma unroll
  for (int m = 0; m < 4; ++m) Qo[j * 32 + i0 + m] = Q[buf][j][i0 + m];
}

// ---------------------------------------------------------------------------
// 1.5a: group products R_g = Q_{g*GSIZE+GSIZE-1} ... Q_{g*GSIZE}
// ---------------------------------------------------------------------------
__global__ __launch_bounds__(256) void k_comb1(float* __restrict__ ws)
{
  const int g = blockIdx.x, tid = threadIdx.x;
  const int j = tid & 31, i0 = (tid >> 5) * 4;
  __shared__ __align__(16) float R[2][32][36];
  __shared__ float red[4];
  const float* Qs = ws + OFF_Q;
  {
    const float* q0 = Qs + (size_t)(g * GSIZE) * 1024;
#pragma unroll
    for (int m = 0; m < 4; ++m) R[0][j][i0 + m] = q0[j * 32 + i0 + m];
  }
  __syncthreads();
  int buf = 0;
  for (int c = 1; c < GSIZE; ++c) {
    const float* qc = Qs + (size_t)(g * GSIZE + c) * 1024 + j * 32;
    float qr[32];
#pragma unroll
    for (int k8 = 0; k8 < 8; ++k8) {
      float4 q4 = *(const float4*)(qc + k8 * 4);
      qr[k8 * 4 + 0] = q4.x; qr[k8 * 4 + 1] = q4.y;
      qr[k8 * 4 + 2] = q4.z; qr[k8 * 4 + 3] = q4.w;
    }
    float a0 = 0.f, a1 = 0.f, a2 = 0.f, a3 = 0.f;
#pragma unroll
    for (int k = 0; k < 32; ++k) {
      float4 r4 = *(const float4*)&R[buf][k][i0];
      float w = qr[k];
      a0 += w * r4.x; a1 += w * r4.y; a2 += w * r4.z; a3 += w * r4.w;
    }
    if ((c & 3) == 3) {
      float ps = a0 + a1 + a2 + a3;
#pragma unroll
      for (int o = 1; o < 64; o <<= 1) ps += __shfl_xor(ps, o);
      if ((tid & 63) == 0) red[tid >> 6] = ps;
      __syncthreads();
      float gs = __builtin_amdgcn_rcpf(red[0] + red[1] + red[2] + red[3]);
      a0 *= gs; a1 *= gs; a2 *= gs; a3 *= gs;
    }
    float4 o4 = {a0, a1, a2, a3};
    *(float4*)&R[buf ^ 1][j][i0] = o4;
    __syncthreads();
    buf ^= 1;
  }
  float* Ro = ws + OFF_R + (size_t)g * 1024;
#pragma unroll
  for (int m = 0; m < 4; ++m) Ro[j * 32 + i0 + m] = R[buf][j][i0 + m];
}

// ---------------------------------------------------------------------------
// 1.5b: one wave scans the GROUPS group-matrices -> state at each group start
// ---------------------------------------------------------------------------
__global__ __launch_bounds__(64) void k_comb2(const float* __restrict__ pi,
                                              float* __restrict__ ws)
{
  const int lane = threadIdx.x;
  if (lane >= 32) return;
  const float* Rg = ws + OFF_R;
  float* xg = ws + OFF_XG;
  float x = pi[lane];
  for (int g = 0; g < GROUPS; ++g) {
    xg[g * 32 + lane] = x;
    const float* rr = Rg + (size_t)g * 1024 + lane * 32;
    float y = 0.f;
#pragma unroll
    for (int k = 0; k < 32; ++k) y += rr[k] * __shfl(x, k);
    float s = y;
#pragma unroll
    for (int o = 1; o < 32; o <<= 1) s += __shfl_xor(s, o);
    x = y / s;
  }
}

// ---------------------------------------------------------------------------
// 1.5c: within each group, scan chunk matrices -> state at each chunk start
// ---------------------------------------------------------------------------
__global__ __launch_bounds__(64) void k_comb3(float* __restrict__ ws)
{
  const int g = blockIdx.x, lane = threadIdx.x;
  if (lane >= 32) return;
  const float* Qs = ws + OFF_Q;
  float* e0 = ws + OFF_E0;
  float x = ws[OFF_XG + g * 32 + lane];
  for (int c = 0; c < GSIZE; ++c) {
    int cc = g * GSIZE + c;
    e0[cc * 32 + lane] = x;
    const float* qr = Qs + (size_t)cc * 1024 + lane * 32;
    float y = 0.f;
#pragma unroll
    for (int k = 0; k < 32; ++k) y += qr[k] * __shfl(x, k);
    float s = y;
#pragma unroll
    for (int o = 1; o < 32; o <<= 1) s += __shfl_xor(s, o);
    x = y / s;
  }
}

// ---------------------------------------------------------------------------
// Phase 2: per-chunk replay with matvecs; loss_t = (u^2 . W2^T x)/(u . W^T x)
// One wave per chunk; lane j holds columns W[:,j], W2[:,j] in registers.
// ---------------------------------------------------------------------------
__global__ __launch_bounds__(64) void k_phase2(float* __restrict__ ws,
                                               float* __restrict__ out)
{
  const int b = blockIdx.x, lane = threadIdx.x;
  if (lane >= 32) return;
  const int j = lane;
  const float* Wg  = ws + OFF_W;
  const float* W2g = ws + OFF_W2;
  const float* cts = ws + OFF_CT;
  float Wc[32], W2c[32];
#pragma unroll
  for (int k = 0; k < 32; ++k) {
    Wc[k]  = Wg[k * 32 + j];
    W2c[k] = W2g[k * 32 + j];
  }
  const float i2v = ws[OFF_I2V + j];
  __shared__ __align__(16) float xs[32];
  xs[j] = ws[OFF_E0 + (size_t)b * 32 + j];
  __syncthreads();
  float lossacc = 0.f;
  const int t0 = b * CLEN;
  for (int s = 0; s < CLEN; ++s) {
    float ct = cts[t0 + s];
    float u  = exp2f(-ct * i2v * LOG2E);
    float xk[32];
    const float4* xv = (const float4*)xs;
#pragma unroll
    for (int k8 = 0; k8 < 8; ++k8) {
      float4 q = xv[k8];
      xk[k8 * 4 + 0] = q.x; xk[k8 * 4 + 1] = q.y;
      xk[k8 * 4 + 2] = q.z; xk[k8 * 4 + 3] = q.w;
    }
    float v = 0.f, w2 = 0.f;
#pragma unroll
    for (int k = 0; k < 32; ++k) {
      v  += Wc[k]  * xk[k];
      w2 += W2c[k] * xk[k];
    }
    float numj = u * v;
    float n2j  = u * u * w2;
    float S = numj, N2 = n2j;
#pragma unroll
    for (int o = 1; o < 32; o <<= 1) {
      S  += __shfl_xor(S, o);
      N2 += __shfl_xor(N2, o);
    }
    float rs = __builtin_amdgcn_rcpf(S);
    lossacc += N2 * rs;
    __syncthreads();          // all xs reads done before overwrite
    xs[j] = numj * rs;        // normalized next state
    __syncthreads();
  }
  if (lane == 0) atomicAdd(out, lossacc);
}

extern "C" void kernel_launch(void* const* d_in, const int* in_sizes, int n_in,
                              void* d_out, int out_size, void* d_ws, size_t ws_size,
                              hipStream_t stream)
{
  (void)in_sizes; (void)n_in; (void)ws_size;
  const float* obs2 = (const float*)d_in[0];
  const float* obs1 = (const float*)d_in[1];
  const float* mean = (const float*)d_in[2];
  const float* var  = (const float*)d_in[3];
  const float* bate = (const float*)d_in[4];
  const float* pi   = (const float*)d_in[5];
  const float* aij  = (const float*)d_in[6];
  float* ws  = (float*)d_ws;
  float* out = (float*)d_out;

  hipMemsetAsync(out, 0, sizeof(float) * out_size, stream);
  const int prep_blocks = (TN + 255) / 256 + 1;
  k_prep<<<prep_blocks, 256, 0, stream>>>(obs2, obs1, mean, var, bate, aij, ws);
  k_phase1<<<CHUNKS, 256, 0, stream>>>(ws);
  k_comb1<<<GROUPS, 256, 0, stream>>>(ws);
  k_comb2<<<1, 64, 0, stream>>>(pi, ws);
  k_comb3<<<GROUPS, 64, 0, stream>>>(ws);
  k_phase2<<<CHUNKS, 64, 0, stream>>>(ws, out);
}

// Round 2
// 361.519 us; speedup vs baseline: 1.0063x; 1.0063x over previous
//
#include <hip/hip_runtime.h>

constexpr int TN     = 100000;
constexpr int CHUNKS = 1000;
constexpr int CLEN   = 100;   // CHUNKS*CLEN == TN
constexpr int GROUPS = 40;
constexpr int GSIZE  = 25;    // GROUPS*GSIZE == CHUNKS

constexpr float LOG2E = 1.4426950408889634f;

// float offsets into ws
constexpr size_t OFF_W   = 0;                              // 32x32
constexpr size_t OFF_W2  = 1024;                           // 32x32
constexpr size_t OFF_I2V = 2048;                           // 32 (i2v * LOG2E)
constexpr size_t OFF_Q   = 4096;                           // CHUNKS*1024
constexpr size_t OFF_R   = OFF_Q + (size_t)CHUNKS * 1024;  // GROUPS*1024
constexpr size_t OFF_XG  = OFF_R + (size_t)GROUPS * 1024;  // GROUPS*32
constexpr size_t OFF_E0  = OFF_XG + (size_t)GROUPS * 32;   // CHUNKS*32

// ---------------------------------------------------------------------------
// Prep (1 block, 256 thr): W[i][j] = aij*A_j*B_ij, W2 = W*A_j*B_ij, i2v*LOG2E
// ---------------------------------------------------------------------------
__global__ __launch_bounds__(256) void k_prep(
    const float* __restrict__ mean, const float* __restrict__ var,
    const float* __restrict__ bate_p, const float* __restrict__ aij,
    float* __restrict__ ws)
{
  const int tid = threadIdx.x;
  const int j = tid & 31, ig = tid >> 5;
  float vj   = var[j];
  float i2v  = 0.5f / vj;
  float norm = rsqrtf(2.0f * 3.1415926f * vj);
  float Aj   = norm * expf(mean[j] * i2v);
  float bate = bate_p[0];
  if (tid < 32) ws[OFF_I2V + tid] = i2v * LOG2E;
#pragma unroll
  for (int m = 0; m < 4; ++m) {
    int i = ig * 4 + m;
    float Bij = expf(-bate * mean[i] * i2v);
    float w = aij[i * 32 + j] * Aj * Bij;
    ws[OFF_W  + i * 32 + j] = w;
    ws[OFF_W2 + i * 32 + j] = w * Aj * Bij;
  }
}

// ---------------------------------------------------------------------------
// Phase 1: one WAVE per chunk. Lane (jt,it) owns a 4x4 output tile and holds
// W columns 4jt..4jt+3 in 128 VGPRs. Q (32x32) double-buffered in LDS.
// Q_new[j,i] = u_j * sum_k W[k,j] * Q[k,i].  Normalized product written out.
// ---------------------------------------------------------------------------
__global__ __launch_bounds__(64) void k_phase1(
    const float* __restrict__ obs2, const float* __restrict__ obs1,
    const float* __restrict__ bate_p, float* __restrict__ ws)
{
  const int b = blockIdx.x, lane = threadIdx.x;
  const int jt = lane >> 3, it = lane & 7;
  const int j0 = jt * 4, i0 = it * 4;
  __shared__ __align__(16) float Q[2][32][36];
  __shared__ float cts[CLEN];

  const int t0 = b * CLEN;
  {
    float bate = bate_p[0];
    for (int l = lane; l < CLEN; l += 64)
      cts[l] = obs2[t0 + l] - bate * obs1[t0 + l];
  }
  // W columns for rows of output this lane computes
  float4 Wr[32];
  const float* Wg = ws + OFF_W;
#pragma unroll
  for (int k = 0; k < 32; ++k) Wr[k] = *(const float4*)&Wg[k * 32 + j0];
  float4 i2vl = *(const float4*)&ws[OFF_I2V + j0];

#pragma unroll
  for (int m = 0; m < 4; ++m) {
    float4 v;
    v.x = (j0 + m == i0 + 0) ? 1.0f : 0.0f;
    v.y = (j0 + m == i0 + 1) ? 1.0f : 0.0f;
    v.z = (j0 + m == i0 + 2) ? 1.0f : 0.0f;
    v.w = (j0 + m == i0 + 3) ? 1.0f : 0.0f;
    *(float4*)&Q[0][j0 + m][i0] = v;
  }
  __syncthreads();

  int buf = 0;
  for (int s = 0; s < CLEN; ++s) {
    float ct = cts[s];
    float4 a0 = {0,0,0,0}, a1 = {0,0,0,0}, a2 = {0,0,0,0}, a3 = {0,0,0,0};
#pragma unroll
    for (int k = 0; k < 32; ++k) {
      float4 q = *(const float4*)&Q[buf][k][i0];
      float4 w = Wr[k];
      a0.x += w.x * q.x; a0.y += w.x * q.y; a0.z += w.x * q.z; a0.w += w.x * q.w;
      a1.x += w.y * q.x; a1.y += w.y * q.y; a1.z += w.y * q.z; a1.w += w.y * q.w;
      a2.x += w.z * q.x; a2.y += w.z * q.y; a2.z += w.z * q.z; a2.w += w.z * q.w;
      a3.x += w.w * q.x; a3.y += w.w * q.y; a3.z += w.w * q.z; a3.w += w.w * q.w;
    }
    float u0 = exp2f(-ct * i2vl.x), u1 = exp2f(-ct * i2vl.y);
    float u2 = exp2f(-ct * i2vl.z), u3 = exp2f(-ct * i2vl.w);
    a0.x *= u0; a0.y *= u0; a0.z *= u0; a0.w *= u0;
    a1.x *= u1; a1.y *= u1; a1.z *= u1; a1.w *= u1;
    a2.x *= u2; a2.y *= u2; a2.z *= u2; a2.w *= u2;
    a3.x *= u3; a3.y *= u3; a3.z *= u3; a3.w *= u3;
    if (((s & 7) == 7) || s == CLEN - 1) {   // scale-invariant rescale
      float ps = a0.x + a0.y + a0.z + a0.w + a1.x + a1.y + a1.z + a1.w
               + a2.x + a2.y + a2.z + a2.w + a3.x + a3.y + a3.z + a3.w;
#pragma unroll
      for (int o = 1; o < 64; o <<= 1) ps += __shfl_xor(ps, o);
      float g = __builtin_amdgcn_rcpf(ps);
      a0.x *= g; a0.y *= g; a0.z *= g; a0.w *= g;
      a1.x *= g; a1.y *= g; a1.z *= g; a1.w *= g;
      a2.x *= g; a2.y *= g; a2.z *= g; a2.w *= g;
      a3.x *= g; a3.y *= g; a3.z *= g; a3.w *= g;
    }
    *(float4*)&Q[buf ^ 1][j0 + 0][i0] = a0;
    *(float4*)&Q[buf ^ 1][j0 + 1][i0] = a1;
    *(float4*)&Q[buf ^ 1][j0 + 2][i0] = a2;
    *(float4*)&Q[buf ^ 1][j0 + 3][i0] = a3;
    __syncthreads();
    buf ^= 1;
  }
  float* Qo = ws + OFF_Q + (size_t)b * 1024;
#pragma unroll
  for (int m = 0; m < 4; ++m)
    *(float4*)&Qo[(j0 + m) * 32 + i0] = *(const float4*)&Q[buf][j0 + m][i0];
}

// ---------------------------------------------------------------------------
// comb1: one wave per group; R_g = Q_last ... Q_first (register-blocked)
// R_new[j,i] = sum_k Qc[j,k] * R[k,i]
// ---------------------------------------------------------------------------
__global__ __launch_bounds__(64) void k_comb1(float* __restrict__ ws)
{
  const int g = blockIdx.x, lane = threadIdx.x;
  const int jt = lane >> 3, it = lane & 7;
  const int j0 = jt * 4, i0 = it * 4;
  __shared__ __align__(16) float R[2][32][36];
  const float* Qs = ws + OFF_Q;
  {
    const float* q0 = Qs + (size_t)(g * GSIZE) * 1024;
#pragma unroll
    for (int m = 0; m < 4; ++m)
      *(float4*)&R[0][j0 + m][i0] = *(const float4*)&q0[(j0 + m) * 32 + i0];
  }
  __syncthreads();
  int buf = 0;
  for (int c = 1; c < GSIZE; ++c) {
    const float* qc = Qs + (size_t)(g * GSIZE + c) * 1024;
    float Qv[4][32];
#pragma unroll
    for (int m = 0; m < 4; ++m)
#pragma unroll
      for (int kk = 0; kk < 8; ++kk) {
        float4 t = *(const float4*)&qc[(j0 + m) * 32 + kk * 4];
        Qv[m][kk * 4 + 0] = t.x; Qv[m][kk * 4 + 1] = t.y;
        Qv[m][kk * 4 + 2] = t.z; Qv[m][kk * 4 + 3] = t.w;
      }
    float4 a0 = {0,0,0,0}, a1 = {0,0,0,0}, a2 = {0,0,0,0}, a3 = {0,0,0,0};
#pragma unroll
    for (int k = 0; k < 32; ++k) {
      float4 r = *(const float4*)&R[buf][k][i0];
      a0.x += Qv[0][k] * r.x; a0.y += Qv[0][k] * r.y; a0.z += Qv[0][k] * r.z; a0.w += Qv[0][k] * r.w;
      a1.x += Qv[1][k] * r.x; a1.y += Qv[1][k] * r.y; a1.z += Qv[1][k] * r.z; a1.w += Qv[1][k] * r.w;
      a2.x += Qv[2][k] * r.x; a2.y += Qv[2][k] * r.y; a2.z += Qv[2][k] * r.z; a2.w += Qv[2][k] * r.w;
      a3.x += Qv[3][k] * r.x; a3.y += Qv[3][k] * r.y; a3.z += Qv[3][k] * r.z; a3.w += Qv[3][k] * r.w;
    }
    if (((c & 7) == 7) || c == GSIZE - 1) {
      float ps = a0.x + a0.y + a0.z + a0.w + a1.x + a1.y + a1.z + a1.w
               + a2.x + a2.y + a2.z + a2.w + a3.x + a3.y + a3.z + a3.w;
#pragma unroll
      for (int o = 1; o < 64; o <<= 1) ps += __shfl_xor(ps, o);
      float gg = __builtin_amdgcn_rcpf(ps);
      a0.x *= gg; a0.y *= gg; a0.z *= gg; a0.w *= gg;
      a1.x *= gg; a1.y *= gg; a1.z *= gg; a1.w *= gg;
      a2.x *= gg; a2.y *= gg; a2.z *= gg; a2.w *= gg;
      a3.x *= gg; a3.y *= gg; a3.z *= gg; a3.w *= gg;
    }
    *(float4*)&R[buf ^ 1][j0 + 0][i0] = a0;
    *(float4*)&R[buf ^ 1][j0 + 1][i0] = a1;
    *(float4*)&R[buf ^ 1][j0 + 2][i0] = a2;
    *(float4*)&R[buf ^ 1][j0 + 3][i0] = a3;
    __syncthreads();
    buf ^= 1;
  }
  float* Ro = ws + OFF_R + (size_t)g * 1024;
#pragma unroll
  for (int m = 0; m < 4; ++m)
    *(float4*)&Ro[(j0 + m) * 32 + i0] = *(const float4*)&R[buf][j0 + m][i0];
}

// ---------------------------------------------------------------------------
// comb2: single wave scans group matrices. Lane (j,h): half-dot over 16 k.
// ---------------------------------------------------------------------------
__global__ __launch_bounds__(64) void k_comb2(const float* __restrict__ pi,
                                              float* __restrict__ ws)
{
  const int lane = threadIdx.x;
  const int j = lane & 31, h = lane >> 5;
  float x = pi[j];  // valid on lanes 0-31 (dup on 32-63, unused as shfl source)
  for (int g = 0; g < GROUPS; ++g) {
    if (lane < 32) ws[OFF_XG + g * 32 + j] = x;
    const float* rr = ws + OFF_R + (size_t)g * 1024 + j * 32 + h * 16;
    const float4* rv = (const float4*)rr;
    float y = 0.f;
#pragma unroll
    for (int q = 0; q < 4; ++q) {
      float4 r4 = rv[q];
      y += r4.x * __shfl(x, h * 16 + q * 4 + 0);
      y += r4.y * __shfl(x, h * 16 + q * 4 + 1);
      y += r4.z * __shfl(x, h * 16 + q * 4 + 2);
      y += r4.w * __shfl(x, h * 16 + q * 4 + 3);
    }
    y += __shfl_xor(y, 32);          // combine k-halves -> full dot y_j
    float s = y;
#pragma unroll
    for (int o = 1; o < 32; o <<= 1) s += __shfl_xor(s, o);
    x = y * __builtin_amdgcn_rcpf(s);
  }
}

// ---------------------------------------------------------------------------
// comb3: per-group scan of chunk matrices -> chunk-start states e0
// ---------------------------------------------------------------------------
__global__ __launch_bounds__(64) void k_comb3(float* __restrict__ ws)
{
  const int g = blockIdx.x, lane = threadIdx.x;
  const int j = lane & 31, h = lane >> 5;
  const float* Qs = ws + OFF_Q;
  float* e0 = ws + OFF_E0;
  float x = ws[OFF_XG + g * 32 + j];
  for (int c = 0; c < GSIZE; ++c) {
    int cc = g * GSIZE + c;
    if (lane < 32) e0[(size_t)cc * 32 + j] = x;
    const float* qr = Qs + (size_t)cc * 1024 + j * 32 + h * 16;
    const float4* qv = (const float4*)qr;
    float y = 0.f;
#pragma unroll
    for (int q = 0; q < 4; ++q) {
      float4 r4 = qv[q];
      y += r4.x * __shfl(x, h * 16 + q * 4 + 0);
      y += r4.y * __shfl(x, h * 16 + q * 4 + 1);
      y += r4.z * __shfl(x, h * 16 + q * 4 + 2);
      y += r4.w * __shfl(x, h * 16 + q * 4 + 3);
    }
    y += __shfl_xor(y, 32);
    float s = y;
#pragma unroll
    for (int o = 1; o < 32; o <<= 1) s += __shfl_xor(s, o);
    x = y * __builtin_amdgcn_rcpf(s);
  }
}

// ---------------------------------------------------------------------------
// Phase 2: one wave per chunk. Half 0 computes u.W^T x, half 1 u^2.W2^T x.
// loss_t = N2/S; x normalized by 1/S. One barrier/step (double-buffered x).
// ---------------------------------------------------------------------------
__global__ __launch_bounds__(64) void k_phase2(
    const float* __restrict__ obs2, const float* __restrict__ obs1,
    const float* __restrict__ bate_p, float* __restrict__ ws,
    float* __restrict__ out)
{
  const int b = blockIdx.x, lane = threadIdx.x;
  const int j = lane & 31, h = lane >> 5;
  __shared__ float cts[CLEN];
  __shared__ __align__(16) float xs[2][32];
  const int t0 = b * CLEN;
  {
    float bate = bate_p[0];
    for (int l = lane; l < CLEN; l += 64)
      cts[l] = obs2[t0 + l] - bate * obs1[t0 + l];
  }
  float Wc[32];
  const float* Wsel = ws + (h ? OFF_W2 : OFF_W);
#pragma unroll
  for (int k = 0; k < 32; ++k) Wc[k] = Wsel[k * 32 + j];
  const float i2vl = ws[OFF_I2V + j];
  if (lane < 32) xs[0][j] = ws[OFF_E0 + (size_t)b * 32 + j];
  __syncthreads();

  float lossacc = 0.f;
  int buf = 0;
  for (int s = 0; s < CLEN; ++s) {
    float ct = cts[s];
    float u  = exp2f(-ct * i2vl);
    float xk[32];
    const float4* xv = (const float4*)xs[buf];
#pragma unroll
    for (int k8 = 0; k8 < 8; ++k8) {
      float4 q = xv[k8];
      xk[k8 * 4 + 0] = q.x; xk[k8 * 4 + 1] = q.y;
      xk[k8 * 4 + 2] = q.z; xk[k8 * 4 + 3] = q.w;
    }
    float dot = 0.f;
#pragma unroll
    for (int k = 0; k < 32; ++k) dot += Wc[k] * xk[k];
    float numj = u * dot;                 // meaningful on half 0
    float red  = h ? (u * u * dot) : numj;
#pragma unroll
    for (int o = 1; o < 32; o <<= 1) red += __shfl_xor(red, o);
    float cross = __shfl_xor(red, 32);
    float S  = h ? cross : red;
    float N2 = h ? red   : cross;
    float rs = __builtin_amdgcn_rcpf(S);
    lossacc += N2 * rs;
    if (lane < 32) xs[buf ^ 1][j] = numj * rs;
    __syncthreads();
    buf ^= 1;
  }
  if (lane == 0) atomicAdd(out, lossacc);
}

extern "C" void kernel_launch(void* const* d_in, const int* in_sizes, int n_in,
                              void* d_out, int out_size, void* d_ws, size_t ws_size,
                              hipStream_t stream)
{
  (void)in_sizes; (void)n_in; (void)ws_size;
  const float* obs2 = (const float*)d_in[0];
  const float* obs1 = (const float*)d_in[1];
  const float* mean = (const float*)d_in[2];
  const float* var  = (const float*)d_in[3];
  const float* bate = (const float*)d_in[4];
  const float* pi   = (const float*)d_in[5];
  const float* aij  = (const float*)d_in[6];
  float* ws  = (float*)d_ws;
  float* out = (float*)d_out;

  hipMemsetAsync(out, 0, sizeof(float) * out_size, stream);
  k_prep  <<<1,      256, 0, stream>>>(mean, var, bate, aij, ws);
  k_phase1<<<CHUNKS,  64, 0, stream>>>(obs2, obs1, bate, ws);
  k_comb1 <<<GROUPS,  64, 0, stream>>>(ws);
  k_comb2 <<<1,       64, 0, stream>>>(pi, ws);
  k_comb3 <<<GROUPS,  64, 0, stream>>>(ws);
  k_phase2<<<CHUNKS,  64, 0, stream>>>(obs2, obs1, bate, ws, out);
}